// Round 14
// baseline (106.424 us; speedup 1.0000x reference)
//
#include <hip/hip_runtime.h>
#include <hip/hip_bf16.h>

// EventSpecificTimingHeads: E=16 per-event attention heads on shared features.
// Round 14: BARRIER-FREE attention. K staged once in LDS (40 KB, no restage);
// V read directly from global (L2-resident -- LDS V-cache was pure overhead,
// cf. m169); zero inner __syncthreads -> waves free-run, compiler pipelines
// V loads across kt via vmcnt. exp2-direct softmax, pk2 packing, 2 qf/wave.

#define E_ 16
#define B_ 8
#define S_ 512
#define D_ 128
#define H_ 4
#define DH_ 32
#define H2_ 64
#define M_ (B_ * S_)
// 1/sqrt(32) * log2(e): scores come out of QK^T in log2 domain.
#define QK_SCALE_L2E 0.25503472437616588f

typedef __attribute__((ext_vector_type(4))) short bf16x4;
typedef __attribute__((ext_vector_type(8))) short bf16x8;
typedef __attribute__((ext_vector_type(4))) float f32x4;

__device__ __forceinline__ short f2bf(float f) {
    unsigned u = __builtin_bit_cast(unsigned, f);
    u += 0x7fffu + ((u >> 16) & 1u);   // RNE
    return (short)(u >> 16);
}

// two f32 -> packed 2xbf16 dword via hip intrinsic (compiler emits cvt_pk)
__device__ __forceinline__ unsigned pk2(float lo, float hi) {
    __hip_bfloat162 t = __float22bfloat162_rn(make_float2(lo, hi));
    unsigned r;
    __builtin_memcpy(&r, &t, sizeof(r));
    return r;
}

__device__ __forceinline__ bf16x8 cat8(bf16x4 lo, bf16x4 hi) {
    return __builtin_shufflevector(lo, hi, 0, 1, 2, 3, 4, 5, 6, 7);
}

// ---------------------------------------------------------------------------
// Kernel 0: fp32 -> bf16 convert: x, Wqkv, Wo, W1. (convert once, read many)
// ---------------------------------------------------------------------------
__global__ __launch_bounds__(256) void convert_kernel(
    const float* __restrict__ x, const float* __restrict__ w,
    const float* __restrict__ wo, const float* __restrict__ w1,
    short* __restrict__ xbf, short* __restrict__ wbf,
    short* __restrict__ wobf, short* __restrict__ w1bf)
{
    const int XN  = (M_ * D_) / 8;             // 65536
    const int WN  = (E_ * 3 * D_ * D_) / 8;    // 98304
    const int WON = (E_ * D_ * D_) / 8;        // 32768
    const int W1N = (E_ * H2_ * D_) / 8;       // 16384
    int idx = blockIdx.x * 256 + threadIdx.x;
    const float* src; short* dst; int off;
    if (idx < XN)                        { src = x;  dst = xbf;  off = idx; }
    else if (idx < XN + WN)              { src = w;  dst = wbf;  off = idx - XN; }
    else if (idx < XN + WN + WON)        { src = wo; dst = wobf; off = idx - XN - WN; }
    else if (idx < XN + WN + WON + W1N)  { src = w1; dst = w1bf; off = idx - XN - WN - WON; }
    else return;
    float4 v0 = *(const float4*)&src[(size_t)off * 8];
    float4 v1 = *(const float4*)&src[(size_t)off * 8 + 4];
    bf16x8 o;
    o[0] = f2bf(v0.x); o[1] = f2bf(v0.y); o[2] = f2bf(v0.z); o[3] = f2bf(v0.w);
    o[4] = f2bf(v1.x); o[5] = f2bf(v1.y); o[6] = f2bf(v1.z); o[7] = f2bf(v1.w);
    *(bf16x8*)&dst[(size_t)off * 8] = o;
}

// ---------------------------------------------------------------------------
// Kernel 1: QKV GEMM via MFMA 16x16x32 (bf16 staging reads).
// q scale includes log2e (scores emerge in log2 domain for attn's exp2).
// ---------------------------------------------------------------------------
__global__ __launch_bounds__(256) void qkv_mfma_kernel(
    const short* __restrict__ xbf,   // [4096][128] bf16
    const short* __restrict__ wbf,   // [16][384][128] bf16
    const float* __restrict__ bqkv,  // [16][384]
    short* __restrict__ q, short* __restrict__ k, short* __restrict__ v)
{
    __shared__ __align__(16) char lds[2 * 64 * 136 * 2];
    short (*xs)[136] = (short(*)[136])lds;
    short (*ws)[136] = (short(*)[136])(lds + 64 * 136 * 2);

    const int ct = blockIdx.x;   // 0..5
    const int rt = blockIdx.y;   // 0..63
    const int e  = blockIdx.z;   // 0..15
    const int tid = threadIdx.x;
    const int w    = tid >> 6;
    const int lane = tid & 63;
    const int l15  = lane & 15;
    const int g    = lane >> 4;

    #pragma unroll
    for (int p = 0; p < 4; ++p) {
        int idx = tid + p * 256;
        int row = idx >> 4, c8 = (idx & 15) * 8;
        *(bf16x8*)&xs[row][c8] =
            *(const bf16x8*)&xbf[(size_t)(rt * 64 + row) * 128 + c8];
        *(bf16x8*)&ws[row][c8] =
            *(const bf16x8*)&wbf[((size_t)e * 384 + ct * 64 + row) * 128 + c8];
    }
    __syncthreads();

    const int n0 = (w & 1) * 32;
    const int m0 = (w >> 1) * 32;
    f32x4 acc00 = {0.f,0.f,0.f,0.f}, acc01 = {0.f,0.f,0.f,0.f};
    f32x4 acc10 = {0.f,0.f,0.f,0.f}, acc11 = {0.f,0.f,0.f,0.f};

    #pragma unroll
    for (int kk = 0; kk < 128; kk += 32) {
        bf16x8 A0 = cat8(*(const bf16x4*)&ws[n0      + l15][kk + 4 * g],
                         *(const bf16x4*)&ws[n0      + l15][kk + 16 + 4 * g]);
        bf16x8 A1 = cat8(*(const bf16x4*)&ws[n0 + 16 + l15][kk + 4 * g],
                         *(const bf16x4*)&ws[n0 + 16 + l15][kk + 16 + 4 * g]);
        bf16x8 B0 = cat8(*(const bf16x4*)&xs[m0      + l15][kk + 4 * g],
                         *(const bf16x4*)&xs[m0      + l15][kk + 16 + 4 * g]);
        bf16x8 B1 = cat8(*(const bf16x4*)&xs[m0 + 16 + l15][kk + 4 * g],
                         *(const bf16x4*)&xs[m0 + 16 + l15][kk + 16 + 4 * g]);
        acc00 = __builtin_amdgcn_mfma_f32_16x16x32_bf16(A0, B0, acc00, 0, 0, 0);
        acc01 = __builtin_amdgcn_mfma_f32_16x16x32_bf16(A0, B1, acc01, 0, 0, 0);
        acc10 = __builtin_amdgcn_mfma_f32_16x16x32_bf16(A1, B0, acc10, 0, 0, 0);
        acc11 = __builtin_amdgcn_mfma_f32_16x16x32_bf16(A1, B1, acc11, 0, 0, 0);
    }

    if (ct < 4) {
        short* dst = (ct < 2) ? q : k;
        const float scale = (ct < 2) ? QK_SCALE_L2E : 1.0f;
        #define STORE_QK(ACC, NS, MS) {                                          \
            const int jb = ct * 64 + n0 + (NS) * 16 + 4 * g;                     \
            const int d  = jb & 127;                                             \
            const int h  = d >> 5, dh = d & 31;                                  \
            const float b0 = bqkv[e * 384 + jb + 0];                             \
            const float b1 = bqkv[e * 384 + jb + 1];                             \
            const float b2 = bqkv[e * 384 + jb + 2];                             \
            const float b3 = bqkv[e * 384 + jb + 3];                             \
            const int m  = rt * 64 + m0 + (MS) * 16 + l15;                       \
            const int bb = m >> 9, s = m & 511;                                  \
            bf16x4 o;                                                            \
            o[0] = f2bf((ACC[0] + b0) * scale);                                  \
            o[1] = f2bf((ACC[1] + b1) * scale);                                  \
            o[2] = f2bf((ACC[2] + b2) * scale);                                  \
            o[3] = f2bf((ACC[3] + b3) * scale);                                  \
            *(bf16x4*)&dst[((((size_t)e * B_ + bb) * H_ + h) * S_ + s) * DH_ + dh] = o; \
        }
        STORE_QK(acc00, 0, 0); STORE_QK(acc01, 0, 1);
        STORE_QK(acc10, 1, 0); STORE_QK(acc11, 1, 1);
        #undef STORE_QK
    } else {
        __syncthreads();
        float (*rp)[68] = (float(*)[68])lds;
        #define RP(ACC, NS, MS) {                                                \
            const int jl = n0 + (NS) * 16 + 4 * g;                               \
            const int ml = m0 + (MS) * 16 + l15;                                 \
            rp[jl + 0][ml] = ACC[0]; rp[jl + 1][ml] = ACC[1];                    \
            rp[jl + 2][ml] = ACC[2]; rp[jl + 3][ml] = ACC[3];                    \
        }
        RP(acc00, 0, 0); RP(acc01, 0, 1); RP(acc10, 1, 0); RP(acc11, 1, 1);
        #undef RP
        __syncthreads();
        const int bb = (rt * 64) >> 9;
        const int sb = (rt * 64) & 511;
        #pragma unroll
        for (int p = 0; p < 2; ++p) {
            int task = tid + p * 256;
            int jl = task >> 3, sc = (task & 7) * 8;
            const int col = ct * 64 + jl;
            const int d = col & 127, h = d >> 5, dh = d & 31;
            const float bias = bqkv[e * 384 + col];
            bf16x8 o;
            #pragma unroll
            for (int j = 0; j < 8; ++j) o[j] = f2bf(rp[jl][sc + j] + bias);
            *(bf16x8*)&v[((((size_t)e * B_ + bb) * H_ + h) * DH_ + dh) * S_ + sb + sc] = o;
        }
    }
}

// ---------------------------------------------------------------------------
// Kernel 2: flash attention, BARRIER-FREE main loop.
// Grid (qhalf, bh, e); 8 waves x 32 q-rows (2 qf/wave). K staged ONCE in LDS
// (40 KB); V^T read directly from global (L2-hot). One __syncthreads total.
// ---------------------------------------------------------------------------
__global__ __launch_bounds__(512) void attn_kernel(
    const short* __restrict__ q, const short* __restrict__ k,
    const short* __restrict__ vt, short* __restrict__ ctxbf)
{
    __shared__ alignas(16) short Ks[512][40];    // full K, 40 KB

    const int qh  = blockIdx.x;   // 0..1 (q half)
    const int bh  = blockIdx.y;   // 0..31
    const int e   = blockIdx.z;   // 0..15
    const int tid = threadIdx.x;
    const int w    = tid >> 6;
    const int lane = tid & 63;
    const int l15  = lane & 15;
    const int g    = lane >> 4;

    const size_t base = ((size_t)e * 32 + bh) * (S_ * DH_);
    const short* qg = q  + base;
    const short* kg = k  + base;
    const short* vg = vt + base;

    // ---- stage full K: thread t copies row t's 64 B ----
    {
        const uint4* src = (const uint4*)(kg + (size_t)tid * DH_);
        uint4* dst = (uint4*)((char*)&Ks[0][0] + (size_t)tid * 80);
        dst[0] = src[0]; dst[1] = src[1]; dst[2] = src[2]; dst[3] = src[3];
    }
    // ---- Q fragments: 2 per wave (rows qh*256 + w*32 + qf*16 + l15) ----
    bf16x8 bq[2];
    #pragma unroll
    for (int qf = 0; qf < 2; ++qf) {
        const short* qp = qg + (size_t)(qh * 256 + w * 32 + qf * 16 + l15) * DH_;
        bq[qf] = cat8(*(const bf16x4*)(qp + 4 * g),
                      *(const bf16x4*)(qp + 16 + 4 * g));
    }
    __syncthreads();   // the ONLY barrier

    f32x4 acc0[2] = {}, acc1[2] = {};
    float lsum[2] = {0.f, 0.f};

    #pragma unroll 2
    for (int kt = 0; kt < 16; ++kt) {   // 32 keys per step, no barriers
        bf16x8 ka[2];
        #pragma unroll
        for (int tt = 0; tt < 2; ++tt) {
            const int row_l = (kt * 2 + tt) * 16 + l15;
            const char* kp = (const char*)&Ks[0][0] + (size_t)row_l * 80 + g * 8;
            ka[tt] = cat8(*(const bf16x4*)kp, *(const bf16x4*)(kp + 32));
        }
        const int keyb = kt * 32;
        // V^T direct from global: rows l15 and l15+16, cols keyb+4g (+16)
        const short* vgp = vg + (size_t)l15 * S_ + keyb + 4 * g;
        bf16x8 va0 = cat8(*(const bf16x4*)vgp, *(const bf16x4*)(vgp + 16));
        const short* vgp1 = vgp + 16 * S_;
        bf16x8 va1 = cat8(*(const bf16x4*)vgp1, *(const bf16x4*)(vgp1 + 16));

        #pragma unroll
        for (int qf = 0; qf < 2; ++qf) {
            f32x4 z = {0.f, 0.f, 0.f, 0.f};
            f32x4 s0 = __builtin_amdgcn_mfma_f32_16x16x32_bf16(ka[0], bq[qf], z, 0, 0, 0);
            f32x4 s1 = __builtin_amdgcn_mfma_f32_16x16x32_bf16(ka[1], bq[qf], z, 0, 0, 0);
            float p0 = __builtin_amdgcn_exp2f(s0[0]);
            float p1 = __builtin_amdgcn_exp2f(s0[1]);
            float p2 = __builtin_amdgcn_exp2f(s0[2]);
            float p3 = __builtin_amdgcn_exp2f(s0[3]);
            float p4 = __builtin_amdgcn_exp2f(s1[0]);
            float p5 = __builtin_amdgcn_exp2f(s1[1]);
            float p6 = __builtin_amdgcn_exp2f(s1[2]);
            float p7 = __builtin_amdgcn_exp2f(s1[3]);
            lsum[qf] += ((p0 + p1) + (p2 + p3)) + ((p4 + p5) + (p6 + p7));
            uint4 uu = make_uint4(pk2(p0, p1), pk2(p2, p3),
                                  pk2(p4, p5), pk2(p6, p7));
            bf16x8 pf = __builtin_bit_cast(bf16x8, uu);
            acc0[qf] = __builtin_amdgcn_mfma_f32_16x16x32_bf16(va0, pf, acc0[qf], 0, 0, 0);
            acc1[qf] = __builtin_amdgcn_mfma_f32_16x16x32_bf16(va1, pf, acc1[qf], 0, 0, 0);
        }
    }

    // ---- denominators + ctx write (bf16 row-major [e][b][s][128]) ----
    const int b = bh >> 2, h = bh & 3;
    #pragma unroll
    for (int qf = 0; qf < 2; ++qf) {
        float ls = lsum[qf];
        ls += __shfl_xor(ls, 16);
        ls += __shfl_xor(ls, 32);
        const float inv = 1.0f / ls;
        const int qrow = qh * 256 + w * 32 + qf * 16 + l15;
        short* cg = ctxbf + (((size_t)(e * B_ + b) * S_ + qrow) * D_ + h * DH_);
        bf16x4 o0, o1;
        #pragma unroll
        for (int r = 0; r < 4; ++r) {
            o0[r] = f2bf(acc0[qf][r] * inv);
            o1[r] = f2bf(acc1[qf][r] * inv);
        }
        *(bf16x4*)&cg[4 * g]      = o0;
        *(bf16x4*)&cg[16 + 4 * g] = o1;
    }
}

// ---------------------------------------------------------------------------
// Kernel 3: head via MFMA 16x16x32 (bf16 staging reads).
// ---------------------------------------------------------------------------
__global__ __launch_bounds__(256) void head_mfma_kernel(
    const short* __restrict__ ctxbf,  // [E][4096][128] bf16
    const short* __restrict__ wobf,   // [E][128][128] bf16
    const float* __restrict__ bo,     // [E][128]
    const short* __restrict__ w1bf,   // [E][64][128] bf16
    const float* __restrict__ b1,     // [E][64]
    const float* __restrict__ W2,     // [E][64]
    const float* __restrict__ b2,     // [E]
    float* __restrict__ out)          // [B][S][E]
{
    __shared__ alignas(16) short Wos[128][136];
    __shared__ alignas(16) short cts[64][136];

    const int mt  = blockIdx.x;   // 0..63
    const int e   = blockIdx.y;
    const int tid = threadIdx.x;
    const int w    = tid >> 6;
    const int lane = tid & 63;
    const int l15  = lane & 15;
    const int g    = lane >> 4;

    #pragma unroll
    for (int p = 0; p < 8; ++p) {
        int idx = tid + p * 256;
        int row = idx >> 4, c8 = (idx & 15) * 8;
        *(bf16x8*)&Wos[row][c8] =
            *(const bf16x8*)&wobf[((size_t)e * 128 + row) * 128 + c8];
    }
    #pragma unroll
    for (int p = 0; p < 4; ++p) {
        int idx = tid + p * 256;
        int row = idx >> 4, c8 = (idx & 15) * 8;
        *(bf16x8*)&cts[row][c8] =
            *(const bf16x8*)&ctxbf[((size_t)e * M_ + mt * 64 + row) * 128 + c8];
    }
    __syncthreads();

    f32x4 accA[8] = {};
    #pragma unroll
    for (int kk = 0; kk < 128; kk += 32) {
        bf16x8 a = cat8(*(const bf16x4*)&cts[w * 16 + l15][kk + 4 * g],
                        *(const bf16x4*)&cts[w * 16 + l15][kk + 16 + 4 * g]);
        #pragma unroll
        for (int t = 0; t < 8; ++t) {
            bf16x8 bfr = cat8(*(const bf16x4*)&Wos[t * 16 + l15][kk + 4 * g],
                              *(const bf16x4*)&Wos[t * 16 + l15][kk + 16 + 4 * g]);
            accA[t] = __builtin_amdgcn_mfma_f32_16x16x32_bf16(a, bfr, accA[t], 0, 0, 0);
        }
    }
    __syncthreads();

    #pragma unroll
    for (int p = 0; p < 4; ++p) {
        int idx = tid + p * 256;
        int row = idx >> 4, c8 = (idx & 15) * 8;
        *(bf16x8*)&Wos[row][c8] =
            *(const bf16x8*)&w1bf[((size_t)e * 64 + row) * 128 + c8];
    }
    #pragma unroll
    for (int t = 0; t < 8; ++t) {
        const float bov = bo[e * 128 + t * 16 + l15];
        #pragma unroll
        for (int r = 0; r < 4; ++r)
            cts[w * 16 + 4 * g + r][t * 16 + l15] = f2bf(accA[t][r] + bov);
    }
    __syncthreads();

    f32x4 accB[4] = {};
    #pragma unroll
    for (int kk = 0; kk < 128; kk += 32) {
        bf16x8 a = cat8(*(const bf16x4*)&cts[w * 16 + l15][kk + 4 * g],
                        *(const bf16x4*)&cts[w * 16 + l15][kk + 16 + 4 * g]);
        #pragma unroll
        for (int t = 0; t < 4; ++t) {
            bf16x8 bfr = cat8(*(const bf16x4*)&Wos[t * 16 + l15][kk + 4 * g],
                              *(const bf16x4*)&Wos[t * 16 + l15][kk + 16 + 4 * g]);
            accB[t] = __builtin_amdgcn_mfma_f32_16x16x32_bf16(a, bfr, accB[t], 0, 0, 0);
        }
    }

    float b1v[4], w2v[4];
    #pragma unroll
    for (int t = 0; t < 4; ++t) {
        b1v[t] = b1[e * 64 + t * 16 + l15];
        w2v[t] = W2[e * 64 + t * 16 + l15];
    }
    const float b2v = b2[e];
    #pragma unroll
    for (int r = 0; r < 4; ++r) {
        float s = 0.f;
        #pragma unroll
        for (int t = 0; t < 4; ++t)
            s += fmaxf(accB[t][r] + b1v[t], 0.f) * w2v[t];
        s += __shfl_xor(s, 1);
        s += __shfl_xor(s, 2);
        s += __shfl_xor(s, 4);
        s += __shfl_xor(s, 8);
        if (l15 == 0) {
            const int m = mt * 64 + w * 16 + 4 * g + r;
            const int bb = m >> 9, ss = m & 511;
            out[((size_t)(bb * S_ + ss)) * E_ + e] = s + b2v;
        }
    }
}

// ---------------------------------------------------------------------------
extern "C" void kernel_launch(void* const* d_in, const int* in_sizes, int n_in,
                              void* d_out, int out_size, void* d_ws, size_t ws_size,
                              hipStream_t stream) {
    const float* x    = (const float*)d_in[0];
    const float* Wqkv = (const float*)d_in[1];
    const float* bqkv = (const float*)d_in[2];
    const float* Wo   = (const float*)d_in[3];
    const float* bo   = (const float*)d_in[4];
    const float* W1   = (const float*)d_in[5];
    const float* b1   = (const float*)d_in[6];
    const float* W2   = (const float*)d_in[7];
    const float* b2   = (const float*)d_in[8];
    float* out = (float*)d_out;

    const size_t SZ = (size_t)E_ * B_ * H_ * S_ * DH_;  // 8,388,608 elements
    short* qb    = (short*)d_ws;
    short* kb    = qb + SZ;
    short* vtb   = kb + SZ;
    short* ctxbf = vtb + SZ;                 // [E][4096][128] bf16
    short* xbf   = ctxbf + SZ;               // 524288
    short* wbf   = xbf + (size_t)M_ * D_;    // 786432
    short* wobf  = wbf + (size_t)E_ * 3 * D_ * D_;   // 262144
    short* w1bf  = wobf + (size_t)E_ * D_ * D_;      // 131072

    convert_kernel<<<dim3(832), 256, 0, stream>>>(x, Wqkv, Wo, W1, xbf, wbf, wobf, w1bf);
    qkv_mfma_kernel<<<dim3(6, 64, 16), 256, 0, stream>>>(xbf, wbf, bqkv, qb, kb, vtb);
    attn_kernel<<<dim3(2, 32, 16), 512, 0, stream>>>(qb, kb, vtb, ctxbf);
    head_mfma_kernel<<<dim3(64, 16), 256, 0, stream>>>(ctxbf, wobf, bo, w1bf, b1, W2, b2, out);
}

// Round 15
// 75.067 us; speedup vs baseline: 1.4177x; 1.4177x over previous
//
#include <hip/hip_runtime.h>
#include <hip/hip_bf16.h>

// EventSpecificTimingHeads: E=16 per-event attention heads on shared features.
// Round 15: barrier-free attn with K AND V both LDS-resident (74.2 KB dynamic
// LDS via hipFuncSetAttribute). One block per (e,bh), K/V staged exactly once,
// zero inner barriers -> waves free-run (r14's V-from-global regression showed
// V must stay in LDS; this isolates the barrier-lockstep hypothesis cleanly).

#define E_ 16
#define B_ 8
#define S_ 512
#define D_ 128
#define H_ 4
#define DH_ 32
#define H2_ 64
#define M_ (B_ * S_)
// 1/sqrt(32) * log2(e): scores come out of QK^T in log2 domain.
#define QK_SCALE_L2E 0.25503472437616588f

#define ATTN_LDS_BYTES (512 * 80 + 32 * 1040)   // K 40960 + V^T 33280 = 74240

typedef __attribute__((ext_vector_type(4))) short bf16x4;
typedef __attribute__((ext_vector_type(8))) short bf16x8;
typedef __attribute__((ext_vector_type(4))) float f32x4;

__device__ __forceinline__ short f2bf(float f) {
    unsigned u = __builtin_bit_cast(unsigned, f);
    u += 0x7fffu + ((u >> 16) & 1u);   // RNE
    return (short)(u >> 16);
}

// two f32 -> packed 2xbf16 dword via hip intrinsic (compiler emits cvt_pk)
__device__ __forceinline__ unsigned pk2(float lo, float hi) {
    __hip_bfloat162 t = __float22bfloat162_rn(make_float2(lo, hi));
    unsigned r;
    __builtin_memcpy(&r, &t, sizeof(r));
    return r;
}

__device__ __forceinline__ bf16x8 cat8(bf16x4 lo, bf16x4 hi) {
    return __builtin_shufflevector(lo, hi, 0, 1, 2, 3, 4, 5, 6, 7);
}

// ---------------------------------------------------------------------------
// Kernel 0: fp32 -> bf16 convert: x, Wqkv, Wo, W1. (convert once, read many)
// ---------------------------------------------------------------------------
__global__ __launch_bounds__(256) void convert_kernel(
    const float* __restrict__ x, const float* __restrict__ w,
    const float* __restrict__ wo, const float* __restrict__ w1,
    short* __restrict__ xbf, short* __restrict__ wbf,
    short* __restrict__ wobf, short* __restrict__ w1bf)
{
    const int XN  = (M_ * D_) / 8;             // 65536
    const int WN  = (E_ * 3 * D_ * D_) / 8;    // 98304
    const int WON = (E_ * D_ * D_) / 8;        // 32768
    const int W1N = (E_ * H2_ * D_) / 8;       // 16384
    int idx = blockIdx.x * 256 + threadIdx.x;
    const float* src; short* dst; int off;
    if (idx < XN)                        { src = x;  dst = xbf;  off = idx; }
    else if (idx < XN + WN)              { src = w;  dst = wbf;  off = idx - XN; }
    else if (idx < XN + WN + WON)        { src = wo; dst = wobf; off = idx - XN - WN; }
    else if (idx < XN + WN + WON + W1N)  { src = w1; dst = w1bf; off = idx - XN - WN - WON; }
    else return;
    float4 v0 = *(const float4*)&src[(size_t)off * 8];
    float4 v1 = *(const float4*)&src[(size_t)off * 8 + 4];
    bf16x8 o;
    o[0] = f2bf(v0.x); o[1] = f2bf(v0.y); o[2] = f2bf(v0.z); o[3] = f2bf(v0.w);
    o[4] = f2bf(v1.x); o[5] = f2bf(v1.y); o[6] = f2bf(v1.z); o[7] = f2bf(v1.w);
    *(bf16x8*)&dst[(size_t)off * 8] = o;
}

// ---------------------------------------------------------------------------
// Kernel 1: QKV GEMM via MFMA 16x16x32 (bf16 staging reads).
// q scale includes log2e (scores emerge in log2 domain for attn's exp2).
// ---------------------------------------------------------------------------
__global__ __launch_bounds__(256) void qkv_mfma_kernel(
    const short* __restrict__ xbf,   // [4096][128] bf16
    const short* __restrict__ wbf,   // [16][384][128] bf16
    const float* __restrict__ bqkv,  // [16][384]
    short* __restrict__ q, short* __restrict__ k, short* __restrict__ v)
{
    __shared__ __align__(16) char lds[2 * 64 * 136 * 2];
    short (*xs)[136] = (short(*)[136])lds;
    short (*ws)[136] = (short(*)[136])(lds + 64 * 136 * 2);

    const int ct = blockIdx.x;   // 0..5
    const int rt = blockIdx.y;   // 0..63
    const int e  = blockIdx.z;   // 0..15
    const int tid = threadIdx.x;
    const int w    = tid >> 6;
    const int lane = tid & 63;
    const int l15  = lane & 15;
    const int g    = lane >> 4;

    #pragma unroll
    for (int p = 0; p < 4; ++p) {
        int idx = tid + p * 256;
        int row = idx >> 4, c8 = (idx & 15) * 8;
        *(bf16x8*)&xs[row][c8] =
            *(const bf16x8*)&xbf[(size_t)(rt * 64 + row) * 128 + c8];
        *(bf16x8*)&ws[row][c8] =
            *(const bf16x8*)&wbf[((size_t)e * 384 + ct * 64 + row) * 128 + c8];
    }
    __syncthreads();

    const int n0 = (w & 1) * 32;
    const int m0 = (w >> 1) * 32;
    f32x4 acc00 = {0.f,0.f,0.f,0.f}, acc01 = {0.f,0.f,0.f,0.f};
    f32x4 acc10 = {0.f,0.f,0.f,0.f}, acc11 = {0.f,0.f,0.f,0.f};

    #pragma unroll
    for (int kk = 0; kk < 128; kk += 32) {
        bf16x8 A0 = cat8(*(const bf16x4*)&ws[n0      + l15][kk + 4 * g],
                         *(const bf16x4*)&ws[n0      + l15][kk + 16 + 4 * g]);
        bf16x8 A1 = cat8(*(const bf16x4*)&ws[n0 + 16 + l15][kk + 4 * g],
                         *(const bf16x4*)&ws[n0 + 16 + l15][kk + 16 + 4 * g]);
        bf16x8 B0 = cat8(*(const bf16x4*)&xs[m0      + l15][kk + 4 * g],
                         *(const bf16x4*)&xs[m0      + l15][kk + 16 + 4 * g]);
        bf16x8 B1 = cat8(*(const bf16x4*)&xs[m0 + 16 + l15][kk + 4 * g],
                         *(const bf16x4*)&xs[m0 + 16 + l15][kk + 16 + 4 * g]);
        acc00 = __builtin_amdgcn_mfma_f32_16x16x32_bf16(A0, B0, acc00, 0, 0, 0);
        acc01 = __builtin_amdgcn_mfma_f32_16x16x32_bf16(A0, B1, acc01, 0, 0, 0);
        acc10 = __builtin_amdgcn_mfma_f32_16x16x32_bf16(A1, B0, acc10, 0, 0, 0);
        acc11 = __builtin_amdgcn_mfma_f32_16x16x32_bf16(A1, B1, acc11, 0, 0, 0);
    }

    if (ct < 4) {
        short* dst = (ct < 2) ? q : k;
        const float scale = (ct < 2) ? QK_SCALE_L2E : 1.0f;
        #define STORE_QK(ACC, NS, MS) {                                          \
            const int jb = ct * 64 + n0 + (NS) * 16 + 4 * g;                     \
            const int d  = jb & 127;                                             \
            const int h  = d >> 5, dh = d & 31;                                  \
            const float b0 = bqkv[e * 384 + jb + 0];                             \
            const float b1 = bqkv[e * 384 + jb + 1];                             \
            const float b2 = bqkv[e * 384 + jb + 2];                             \
            const float b3 = bqkv[e * 384 + jb + 3];                             \
            const int m  = rt * 64 + m0 + (MS) * 16 + l15;                       \
            const int bb = m >> 9, s = m & 511;                                  \
            bf16x4 o;                                                            \
            o[0] = f2bf((ACC[0] + b0) * scale);                                  \
            o[1] = f2bf((ACC[1] + b1) * scale);                                  \
            o[2] = f2bf((ACC[2] + b2) * scale);                                  \
            o[3] = f2bf((ACC[3] + b3) * scale);                                  \
            *(bf16x4*)&dst[((((size_t)e * B_ + bb) * H_ + h) * S_ + s) * DH_ + dh] = o; \
        }
        STORE_QK(acc00, 0, 0); STORE_QK(acc01, 0, 1);
        STORE_QK(acc10, 1, 0); STORE_QK(acc11, 1, 1);
        #undef STORE_QK
    } else {
        __syncthreads();
        float (*rp)[68] = (float(*)[68])lds;
        #define RP(ACC, NS, MS) {                                                \
            const int jl = n0 + (NS) * 16 + 4 * g;                               \
            const int ml = m0 + (MS) * 16 + l15;                                 \
            rp[jl + 0][ml] = ACC[0]; rp[jl + 1][ml] = ACC[1];                    \
            rp[jl + 2][ml] = ACC[2]; rp[jl + 3][ml] = ACC[3];                    \
        }
        RP(acc00, 0, 0); RP(acc01, 0, 1); RP(acc10, 1, 0); RP(acc11, 1, 1);
        #undef RP
        __syncthreads();
        const int bb = (rt * 64) >> 9;
        const int sb = (rt * 64) & 511;
        #pragma unroll
        for (int p = 0; p < 2; ++p) {
            int task = tid + p * 256;
            int jl = task >> 3, sc = (task & 7) * 8;
            const int col = ct * 64 + jl;
            const int d = col & 127, h = d >> 5, dh = d & 31;
            const float bias = bqkv[e * 384 + col];
            bf16x8 o;
            #pragma unroll
            for (int j = 0; j < 8; ++j) o[j] = f2bf(rp[jl][sc + j] + bias);
            *(bf16x8*)&v[((((size_t)e * B_ + bb) * H_ + h) * DH_ + dh) * S_ + sb + sc] = o;
        }
    }
}

// ---------------------------------------------------------------------------
// Kernel 2: flash attention, barrier-free. One block per (e,bh): 8 waves x
// 64 q-rows (4 qf/wave). Full K (40 KB) + full V^T (33.3 KB) in DYNAMIC LDS,
// staged once; zero inner barriers. exp2-direct softmax, pk2 packing.
// ---------------------------------------------------------------------------
__global__ __launch_bounds__(512) void attn_kernel(
    const short* __restrict__ q, const short* __restrict__ k,
    const short* __restrict__ vt, short* __restrict__ ctxbf)
{
    extern __shared__ __align__(16) char smem[];
    char* Kbase  = smem;            // [512 rows][80 B]
    char* VTbase = smem + 40960;    // [32 rows][1040 B]

    const int bh  = blockIdx.x;   // 0..31
    const int e   = blockIdx.y;   // 0..15
    const int tid = threadIdx.x;
    const int w    = tid >> 6;
    const int lane = tid & 63;
    const int l15  = lane & 15;
    const int g    = lane >> 4;

    const size_t base = ((size_t)e * 32 + bh) * (S_ * DH_);
    const short* qg = q  + base;
    const short* kg = k  + base;
    const short* vg = vt + base;

    // ---- stage full K: thread t copies row t (64 B) ----
    {
        const uint4* src = (const uint4*)(kg + (size_t)tid * DH_);
        uint4* dst = (uint4*)(Kbase + (size_t)tid * 80);
        dst[0] = src[0]; dst[1] = src[1]; dst[2] = src[2]; dst[3] = src[3];
    }
    // ---- stage full V^T: thread t copies 64 B of row (t>>4) ----
    {
        int d = tid >> 4, c0 = (tid & 15) * 32;
        const uint4* src = (const uint4*)(vg + (size_t)d * S_ + c0);
        uint4* dst = (uint4*)(VTbase + (size_t)d * 1040 + c0 * 2);
        dst[0] = src[0]; dst[1] = src[1]; dst[2] = src[2]; dst[3] = src[3];
    }
    // ---- Q fragments: 4 per wave (rows w*64 + qf*16 + l15) ----
    bf16x8 bq[4];
    #pragma unroll
    for (int qf = 0; qf < 4; ++qf) {
        const short* qp = qg + (size_t)(w * 64 + qf * 16 + l15) * DH_;
        bq[qf] = cat8(*(const bf16x4*)(qp + 4 * g),
                      *(const bf16x4*)(qp + 16 + 4 * g));
    }
    __syncthreads();   // the ONLY barrier

    f32x4 acc0[4] = {}, acc1[4] = {};
    float lsum[4] = {0.f, 0.f, 0.f, 0.f};

    for (int kt = 0; kt < 16; ++kt) {   // 32 keys per step, no barriers
        bf16x8 ka[2];
        #pragma unroll
        for (int tt = 0; tt < 2; ++tt) {
            const int row_l = (kt * 2 + tt) * 16 + l15;
            const char* kp = Kbase + (size_t)row_l * 80 + g * 8;
            ka[tt] = cat8(*(const bf16x4*)kp, *(const bf16x4*)(kp + 32));
        }
        const int keyb = kt * 32;
        const char* vp = VTbase + (size_t)l15 * 1040 + (keyb + 4 * g) * 2;
        bf16x8 va0 = cat8(*(const bf16x4*)vp, *(const bf16x4*)(vp + 32));
        const char* vp1 = vp + 16 * 1040;
        bf16x8 va1 = cat8(*(const bf16x4*)vp1, *(const bf16x4*)(vp1 + 32));

        #pragma unroll
        for (int qf = 0; qf < 4; ++qf) {
            f32x4 z = {0.f, 0.f, 0.f, 0.f};
            f32x4 s0 = __builtin_amdgcn_mfma_f32_16x16x32_bf16(ka[0], bq[qf], z, 0, 0, 0);
            f32x4 s1 = __builtin_amdgcn_mfma_f32_16x16x32_bf16(ka[1], bq[qf], z, 0, 0, 0);
            float p0 = __builtin_amdgcn_exp2f(s0[0]);
            float p1 = __builtin_amdgcn_exp2f(s0[1]);
            float p2 = __builtin_amdgcn_exp2f(s0[2]);
            float p3 = __builtin_amdgcn_exp2f(s0[3]);
            float p4 = __builtin_amdgcn_exp2f(s1[0]);
            float p5 = __builtin_amdgcn_exp2f(s1[1]);
            float p6 = __builtin_amdgcn_exp2f(s1[2]);
            float p7 = __builtin_amdgcn_exp2f(s1[3]);
            lsum[qf] += ((p0 + p1) + (p2 + p3)) + ((p4 + p5) + (p6 + p7));
            uint4 uu = make_uint4(pk2(p0, p1), pk2(p2, p3),
                                  pk2(p4, p5), pk2(p6, p7));
            bf16x8 pf = __builtin_bit_cast(bf16x8, uu);
            acc0[qf] = __builtin_amdgcn_mfma_f32_16x16x32_bf16(va0, pf, acc0[qf], 0, 0, 0);
            acc1[qf] = __builtin_amdgcn_mfma_f32_16x16x32_bf16(va1, pf, acc1[qf], 0, 0, 0);
        }
    }

    // ---- denominators + ctx write (bf16 row-major [e][b][s][128]) ----
    const int b = bh >> 2, h = bh & 3;
    #pragma unroll
    for (int qf = 0; qf < 4; ++qf) {
        float ls = lsum[qf];
        ls += __shfl_xor(ls, 16);
        ls += __shfl_xor(ls, 32);
        const float inv = 1.0f / ls;
        const int qrow = w * 64 + qf * 16 + l15;
        short* cg = ctxbf + (((size_t)(e * B_ + b) * S_ + qrow) * D_ + h * DH_);
        bf16x4 o0, o1;
        #pragma unroll
        for (int r = 0; r < 4; ++r) {
            o0[r] = f2bf(acc0[qf][r] * inv);
            o1[r] = f2bf(acc1[qf][r] * inv);
        }
        *(bf16x4*)&cg[4 * g]      = o0;
        *(bf16x4*)&cg[16 + 4 * g] = o1;
    }
}

// ---------------------------------------------------------------------------
// Kernel 3: head via MFMA 16x16x32 (bf16 staging reads).
// ---------------------------------------------------------------------------
__global__ __launch_bounds__(256) void head_mfma_kernel(
    const short* __restrict__ ctxbf,  // [E][4096][128] bf16
    const short* __restrict__ wobf,   // [E][128][128] bf16
    const float* __restrict__ bo,     // [E][128]
    const short* __restrict__ w1bf,   // [E][64][128] bf16
    const float* __restrict__ b1,     // [E][64]
    const float* __restrict__ W2,     // [E][64]
    const float* __restrict__ b2,     // [E]
    float* __restrict__ out)          // [B][S][E]
{
    __shared__ alignas(16) short Wos[128][136];
    __shared__ alignas(16) short cts[64][136];

    const int mt  = blockIdx.x;   // 0..63
    const int e   = blockIdx.y;
    const int tid = threadIdx.x;
    const int w    = tid >> 6;
    const int lane = tid & 63;
    const int l15  = lane & 15;
    const int g    = lane >> 4;

    #pragma unroll
    for (int p = 0; p < 8; ++p) {
        int idx = tid + p * 256;
        int row = idx >> 4, c8 = (idx & 15) * 8;
        *(bf16x8*)&Wos[row][c8] =
            *(const bf16x8*)&wobf[((size_t)e * 128 + row) * 128 + c8];
    }
    #pragma unroll
    for (int p = 0; p < 4; ++p) {
        int idx = tid + p * 256;
        int row = idx >> 4, c8 = (idx & 15) * 8;
        *(bf16x8*)&cts[row][c8] =
            *(const bf16x8*)&ctxbf[((size_t)e * M_ + mt * 64 + row) * 128 + c8];
    }
    __syncthreads();

    f32x4 accA[8] = {};
    #pragma unroll
    for (int kk = 0; kk < 128; kk += 32) {
        bf16x8 a = cat8(*(const bf16x4*)&cts[w * 16 + l15][kk + 4 * g],
                        *(const bf16x4*)&cts[w * 16 + l15][kk + 16 + 4 * g]);
        #pragma unroll
        for (int t = 0; t < 8; ++t) {
            bf16x8 bfr = cat8(*(const bf16x4*)&Wos[t * 16 + l15][kk + 4 * g],
                              *(const bf16x4*)&Wos[t * 16 + l15][kk + 16 + 4 * g]);
            accA[t] = __builtin_amdgcn_mfma_f32_16x16x32_bf16(a, bfr, accA[t], 0, 0, 0);
        }
    }
    __syncthreads();

    #pragma unroll
    for (int p = 0; p < 4; ++p) {
        int idx = tid + p * 256;
        int row = idx >> 4, c8 = (idx & 15) * 8;
        *(bf16x8*)&Wos[row][c8] =
            *(const bf16x8*)&w1bf[((size_t)e * 64 + row) * 128 + c8];
    }
    #pragma unroll
    for (int t = 0; t < 8; ++t) {
        const float bov = bo[e * 128 + t * 16 + l15];
        #pragma unroll
        for (int r = 0; r < 4; ++r)
            cts[w * 16 + 4 * g + r][t * 16 + l15] = f2bf(accA[t][r] + bov);
    }
    __syncthreads();

    f32x4 accB[4] = {};
    #pragma unroll
    for (int kk = 0; kk < 128; kk += 32) {
        bf16x8 a = cat8(*(const bf16x4*)&cts[w * 16 + l15][kk + 4 * g],
                        *(const bf16x4*)&cts[w * 16 + l15][kk + 16 + 4 * g]);
        #pragma unroll
        for (int t = 0; t < 4; ++t) {
            bf16x8 bfr = cat8(*(const bf16x4*)&Wos[t * 16 + l15][kk + 4 * g],
                              *(const bf16x4*)&Wos[t * 16 + l15][kk + 16 + 4 * g]);
            accB[t] = __builtin_amdgcn_mfma_f32_16x16x32_bf16(a, bfr, accB[t], 0, 0, 0);
        }
    }

    float b1v[4], w2v[4];
    #pragma unroll
    for (int t = 0; t < 4; ++t) {
        b1v[t] = b1[e * 64 + t * 16 + l15];
        w2v[t] = W2[e * 64 + t * 16 + l15];
    }
    const float b2v = b2[e];
    #pragma unroll
    for (int r = 0; r < 4; ++r) {
        float s = 0.f;
        #pragma unroll
        for (int t = 0; t < 4; ++t)
            s += fmaxf(accB[t][r] + b1v[t], 0.f) * w2v[t];
        s += __shfl_xor(s, 1);
        s += __shfl_xor(s, 2);
        s += __shfl_xor(s, 4);
        s += __shfl_xor(s, 8);
        if (l15 == 0) {
            const int m = mt * 64 + w * 16 + 4 * g + r;
            const int bb = m >> 9, ss = m & 511;
            out[((size_t)(bb * S_ + ss)) * E_ + e] = s + b2v;
        }
    }
}

// ---------------------------------------------------------------------------
extern "C" void kernel_launch(void* const* d_in, const int* in_sizes, int n_in,
                              void* d_out, int out_size, void* d_ws, size_t ws_size,
                              hipStream_t stream) {
    const float* x    = (const float*)d_in[0];
    const float* Wqkv = (const float*)d_in[1];
    const float* bqkv = (const float*)d_in[2];
    const float* Wo   = (const float*)d_in[3];
    const float* bo   = (const float*)d_in[4];
    const float* W1   = (const float*)d_in[5];
    const float* b1   = (const float*)d_in[6];
    const float* W2   = (const float*)d_in[7];
    const float* b2   = (const float*)d_in[8];
    float* out = (float*)d_out;

    const size_t SZ = (size_t)E_ * B_ * H_ * S_ * DH_;  // 8,388,608 elements
    short* qb    = (short*)d_ws;
    short* kb    = qb + SZ;
    short* vtb   = kb + SZ;
    short* ctxbf = vtb + SZ;                 // [E][4096][128] bf16
    short* xbf   = ctxbf + SZ;               // 524288
    short* wbf   = xbf + (size_t)M_ * D_;    // 786432
    short* wobf  = wbf + (size_t)E_ * 3 * D_ * D_;   // 262144
    short* w1bf  = wobf + (size_t)E_ * D_ * D_;      // 131072

    // allow >64KB dynamic LDS for attn (deterministic, non-stream host call)
    hipFuncSetAttribute((const void*)attn_kernel,
                        hipFuncAttributeMaxDynamicSharedMemorySize,
                        ATTN_LDS_BYTES);

    convert_kernel<<<dim3(832), 256, 0, stream>>>(x, Wqkv, Wo, W1, xbf, wbf, wobf, w1bf);
    qkv_mfma_kernel<<<dim3(6, 64, 16), 256, 0, stream>>>(xbf, wbf, bqkv, qb, kb, vtb);
    attn_kernel<<<dim3(32, 16), 512, ATTN_LDS_BYTES, stream>>>(qb, kb, vtb, ctxbf);
    head_mfma_kernel<<<dim3(64, 16), 256, 0, stream>>>(ctxbf, wobf, bo, w1bf, b1, W2, b2, out);
}

// Round 16
// 74.498 us; speedup vs baseline: 1.4285x; 1.0076x over previous
//
#include <hip/hip_runtime.h>
#include <hip/hip_bf16.h>

// EventSpecificTimingHeads: E=16 per-event attention heads on shared features.
// Round 16: qkv and head widened to 512-thread / 128-row blocks (half the
// blocks, half the W refetch+staging per output row). attn unchanged (r15
// barrier-free K+V-in-LDS). convert unchanged.

#define E_ 16
#define B_ 8
#define S_ 512
#define D_ 128
#define H_ 4
#define DH_ 32
#define H2_ 64
#define M_ (B_ * S_)
// 1/sqrt(32) * log2(e): scores come out of QK^T in log2 domain.
#define QK_SCALE_L2E 0.25503472437616588f

#define ATTN_LDS_BYTES (512 * 80 + 32 * 1040)       // 74240
#define HEAD_LDS_BYTES (128 * 136 * 2 * 2)          // 69632

typedef __attribute__((ext_vector_type(4))) short bf16x4;
typedef __attribute__((ext_vector_type(8))) short bf16x8;
typedef __attribute__((ext_vector_type(4))) float f32x4;

__device__ __forceinline__ short f2bf(float f) {
    unsigned u = __builtin_bit_cast(unsigned, f);
    u += 0x7fffu + ((u >> 16) & 1u);   // RNE
    return (short)(u >> 16);
}

__device__ __forceinline__ unsigned pk2(float lo, float hi) {
    __hip_bfloat162 t = __float22bfloat162_rn(make_float2(lo, hi));
    unsigned r;
    __builtin_memcpy(&r, &t, sizeof(r));
    return r;
}

__device__ __forceinline__ bf16x8 cat8(bf16x4 lo, bf16x4 hi) {
    return __builtin_shufflevector(lo, hi, 0, 1, 2, 3, 4, 5, 6, 7);
}

// ---------------------------------------------------------------------------
// Kernel 0: fp32 -> bf16 convert: x, Wqkv, Wo, W1. (convert once, read many)
// ---------------------------------------------------------------------------
__global__ __launch_bounds__(256) void convert_kernel(
    const float* __restrict__ x, const float* __restrict__ w,
    const float* __restrict__ wo, const float* __restrict__ w1,
    short* __restrict__ xbf, short* __restrict__ wbf,
    short* __restrict__ wobf, short* __restrict__ w1bf)
{
    const int XN  = (M_ * D_) / 8;             // 65536
    const int WN  = (E_ * 3 * D_ * D_) / 8;    // 98304
    const int WON = (E_ * D_ * D_) / 8;        // 32768
    const int W1N = (E_ * H2_ * D_) / 8;       // 16384
    int idx = blockIdx.x * 256 + threadIdx.x;
    const float* src; short* dst; int off;
    if (idx < XN)                        { src = x;  dst = xbf;  off = idx; }
    else if (idx < XN + WN)              { src = w;  dst = wbf;  off = idx - XN; }
    else if (idx < XN + WN + WON)        { src = wo; dst = wobf; off = idx - XN - WN; }
    else if (idx < XN + WN + WON + W1N)  { src = w1; dst = w1bf; off = idx - XN - WN - WON; }
    else return;
    float4 v0 = *(const float4*)&src[(size_t)off * 8];
    float4 v1 = *(const float4*)&src[(size_t)off * 8 + 4];
    bf16x8 o;
    o[0] = f2bf(v0.x); o[1] = f2bf(v0.y); o[2] = f2bf(v0.z); o[3] = f2bf(v0.w);
    o[4] = f2bf(v1.x); o[5] = f2bf(v1.y); o[6] = f2bf(v1.z); o[7] = f2bf(v1.w);
    *(bf16x8*)&dst[(size_t)off * 8] = o;
}

// ---------------------------------------------------------------------------
// Kernel 1: QKV GEMM, 512-thr blocks, 128(m) x 64(n) tiles, K=128.
// 8 waves: m0 = (w>>1)*32, n0 = (w&1)*32. W staged once per 128 rows.
// ---------------------------------------------------------------------------
__global__ __launch_bounds__(512) void qkv_mfma_kernel(
    const short* __restrict__ xbf,   // [4096][128] bf16
    const short* __restrict__ wbf,   // [16][384][128] bf16
    const float* __restrict__ bqkv,  // [16][384]
    short* __restrict__ q, short* __restrict__ k, short* __restrict__ v)
{
    __shared__ __align__(16) char lds[(128 + 64) * 136 * 2];   // 52.2 KB
    short (*xs)[136] = (short(*)[136])lds;
    short (*ws)[136] = (short(*)[136])(lds + 128 * 136 * 2);

    const int ct = blockIdx.x;   // 0..5
    const int rt = blockIdx.y;   // 0..31 (128-row tiles)
    const int e  = blockIdx.z;   // 0..15
    const int tid = threadIdx.x;
    const int w    = tid >> 6;
    const int lane = tid & 63;
    const int l15  = lane & 15;
    const int g    = lane >> 4;

    // stage x tile 128x128 (2048 chunks) + W tile 64x128 (1024 chunks)
    #pragma unroll
    for (int p = 0; p < 4; ++p) {
        int idx = tid + p * 512;
        int row = idx >> 4, c8 = (idx & 15) * 8;
        *(bf16x8*)&xs[row][c8] =
            *(const bf16x8*)&xbf[(size_t)(rt * 128 + row) * 128 + c8];
    }
    #pragma unroll
    for (int p = 0; p < 2; ++p) {
        int idx = tid + p * 512;
        int row = idx >> 4, c8 = (idx & 15) * 8;
        *(bf16x8*)&ws[row][c8] =
            *(const bf16x8*)&wbf[((size_t)e * 384 + ct * 64 + row) * 128 + c8];
    }
    __syncthreads();

    const int n0 = (w & 1) * 32;
    const int m0 = (w >> 1) * 32;   // 0..96
    f32x4 acc00 = {0.f,0.f,0.f,0.f}, acc01 = {0.f,0.f,0.f,0.f};
    f32x4 acc10 = {0.f,0.f,0.f,0.f}, acc11 = {0.f,0.f,0.f,0.f};

    #pragma unroll
    for (int kk = 0; kk < 128; kk += 32) {
        bf16x8 A0 = cat8(*(const bf16x4*)&ws[n0      + l15][kk + 4 * g],
                         *(const bf16x4*)&ws[n0      + l15][kk + 16 + 4 * g]);
        bf16x8 A1 = cat8(*(const bf16x4*)&ws[n0 + 16 + l15][kk + 4 * g],
                         *(const bf16x4*)&ws[n0 + 16 + l15][kk + 16 + 4 * g]);
        bf16x8 B0 = cat8(*(const bf16x4*)&xs[m0      + l15][kk + 4 * g],
                         *(const bf16x4*)&xs[m0      + l15][kk + 16 + 4 * g]);
        bf16x8 B1 = cat8(*(const bf16x4*)&xs[m0 + 16 + l15][kk + 4 * g],
                         *(const bf16x4*)&xs[m0 + 16 + l15][kk + 16 + 4 * g]);
        acc00 = __builtin_amdgcn_mfma_f32_16x16x32_bf16(A0, B0, acc00, 0, 0, 0);
        acc01 = __builtin_amdgcn_mfma_f32_16x16x32_bf16(A0, B1, acc01, 0, 0, 0);
        acc10 = __builtin_amdgcn_mfma_f32_16x16x32_bf16(A1, B0, acc10, 0, 0, 0);
        acc11 = __builtin_amdgcn_mfma_f32_16x16x32_bf16(A1, B1, acc11, 0, 0, 0);
    }

    if (ct < 4) {
        short* dst = (ct < 2) ? q : k;
        const float scale = (ct < 2) ? QK_SCALE_L2E : 1.0f;
        #define STORE_QK(ACC, NS, MS) {                                          \
            const int jb = ct * 64 + n0 + (NS) * 16 + 4 * g;                     \
            const int d  = jb & 127;                                             \
            const int h  = d >> 5, dh = d & 31;                                  \
            const float b0 = bqkv[e * 384 + jb + 0];                             \
            const float b1 = bqkv[e * 384 + jb + 1];                             \
            const float b2 = bqkv[e * 384 + jb + 2];                             \
            const float b3 = bqkv[e * 384 + jb + 3];                             \
            const int m  = rt * 128 + m0 + (MS) * 16 + l15;                      \
            const int bb = m >> 9, s = m & 511;                                  \
            bf16x4 o;                                                            \
            o[0] = f2bf((ACC[0] + b0) * scale);                                  \
            o[1] = f2bf((ACC[1] + b1) * scale);                                  \
            o[2] = f2bf((ACC[2] + b2) * scale);                                  \
            o[3] = f2bf((ACC[3] + b3) * scale);                                  \
            *(bf16x4*)&dst[((((size_t)e * B_ + bb) * H_ + h) * S_ + s) * DH_ + dh] = o; \
        }
        STORE_QK(acc00, 0, 0); STORE_QK(acc01, 0, 1);
        STORE_QK(acc10, 1, 0); STORE_QK(acc11, 1, 1);
        #undef STORE_QK
    } else {
        // v: repack through LDS to transposed [dh][s] layout
        __syncthreads();
        float (*rp)[132] = (float(*)[132])lds;   // [64 ch][128 m + pad] 33.8 KB
        #define RP(ACC, NS, MS) {                                                \
            const int jl = n0 + (NS) * 16 + 4 * g;                               \
            const int ml = m0 + (MS) * 16 + l15;                                 \
            rp[jl + 0][ml] = ACC[0]; rp[jl + 1][ml] = ACC[1];                    \
            rp[jl + 2][ml] = ACC[2]; rp[jl + 3][ml] = ACC[3];                    \
        }
        RP(acc00, 0, 0); RP(acc01, 0, 1); RP(acc10, 1, 0); RP(acc11, 1, 1);
        #undef RP
        __syncthreads();
        const int bb = (rt * 128) >> 9;
        const int sb = (rt * 128) & 511;
        #pragma unroll
        for (int p = 0; p < 2; ++p) {
            int task = tid + p * 512;          // 1024 tasks
            int jl = task >> 4, sc = (task & 15) * 8;
            const int col = ct * 64 + jl;      // 256..383
            const int d = col & 127, h = d >> 5, dh = d & 31;
            const float bias = bqkv[e * 384 + col];
            bf16x8 o;
            #pragma unroll
            for (int j = 0; j < 8; ++j) o[j] = f2bf(rp[jl][sc + j] + bias);
            *(bf16x8*)&v[((((size_t)e * B_ + bb) * H_ + h) * DH_ + dh) * S_ + sb + sc] = o;
        }
    }
}

// ---------------------------------------------------------------------------
// Kernel 2: flash attention, barrier-free (unchanged from r15).
// ---------------------------------------------------------------------------
__global__ __launch_bounds__(512) void attn_kernel(
    const short* __restrict__ q, const short* __restrict__ k,
    const short* __restrict__ vt, short* __restrict__ ctxbf)
{
    extern __shared__ __align__(16) char smem[];
    char* Kbase  = smem;            // [512 rows][80 B]
    char* VTbase = smem + 40960;    // [32 rows][1040 B]

    const int bh  = blockIdx.x;   // 0..31
    const int e   = blockIdx.y;   // 0..15
    const int tid = threadIdx.x;
    const int w    = tid >> 6;
    const int lane = tid & 63;
    const int l15  = lane & 15;
    const int g    = lane >> 4;

    const size_t base = ((size_t)e * 32 + bh) * (S_ * DH_);
    const short* qg = q  + base;
    const short* kg = k  + base;
    const short* vg = vt + base;

    {
        const uint4* src = (const uint4*)(kg + (size_t)tid * DH_);
        uint4* dst = (uint4*)(Kbase + (size_t)tid * 80);
        dst[0] = src[0]; dst[1] = src[1]; dst[2] = src[2]; dst[3] = src[3];
    }
    {
        int d = tid >> 4, c0 = (tid & 15) * 32;
        const uint4* src = (const uint4*)(vg + (size_t)d * S_ + c0);
        uint4* dst = (uint4*)(VTbase + (size_t)d * 1040 + c0 * 2);
        dst[0] = src[0]; dst[1] = src[1]; dst[2] = src[2]; dst[3] = src[3];
    }
    bf16x8 bq[4];
    #pragma unroll
    for (int qf = 0; qf < 4; ++qf) {
        const short* qp = qg + (size_t)(w * 64 + qf * 16 + l15) * DH_;
        bq[qf] = cat8(*(const bf16x4*)(qp + 4 * g),
                      *(const bf16x4*)(qp + 16 + 4 * g));
    }
    __syncthreads();   // the ONLY barrier

    f32x4 acc0[4] = {}, acc1[4] = {};
    float lsum[4] = {0.f, 0.f, 0.f, 0.f};

    for (int kt = 0; kt < 16; ++kt) {
        bf16x8 ka[2];
        #pragma unroll
        for (int tt = 0; tt < 2; ++tt) {
            const int row_l = (kt * 2 + tt) * 16 + l15;
            const char* kp = Kbase + (size_t)row_l * 80 + g * 8;
            ka[tt] = cat8(*(const bf16x4*)kp, *(const bf16x4*)(kp + 32));
        }
        const int keyb = kt * 32;
        const char* vp = VTbase + (size_t)l15 * 1040 + (keyb + 4 * g) * 2;
        bf16x8 va0 = cat8(*(const bf16x4*)vp, *(const bf16x4*)(vp + 32));
        const char* vp1 = vp + 16 * 1040;
        bf16x8 va1 = cat8(*(const bf16x4*)vp1, *(const bf16x4*)(vp1 + 32));

        #pragma unroll
        for (int qf = 0; qf < 4; ++qf) {
            f32x4 z = {0.f, 0.f, 0.f, 0.f};
            f32x4 s0 = __builtin_amdgcn_mfma_f32_16x16x32_bf16(ka[0], bq[qf], z, 0, 0, 0);
            f32x4 s1 = __builtin_amdgcn_mfma_f32_16x16x32_bf16(ka[1], bq[qf], z, 0, 0, 0);
            float p0 = __builtin_amdgcn_exp2f(s0[0]);
            float p1 = __builtin_amdgcn_exp2f(s0[1]);
            float p2 = __builtin_amdgcn_exp2f(s0[2]);
            float p3 = __builtin_amdgcn_exp2f(s0[3]);
            float p4 = __builtin_amdgcn_exp2f(s1[0]);
            float p5 = __builtin_amdgcn_exp2f(s1[1]);
            float p6 = __builtin_amdgcn_exp2f(s1[2]);
            float p7 = __builtin_amdgcn_exp2f(s1[3]);
            lsum[qf] += ((p0 + p1) + (p2 + p3)) + ((p4 + p5) + (p6 + p7));
            uint4 uu = make_uint4(pk2(p0, p1), pk2(p2, p3),
                                  pk2(p4, p5), pk2(p6, p7));
            bf16x8 pf = __builtin_bit_cast(bf16x8, uu);
            acc0[qf] = __builtin_amdgcn_mfma_f32_16x16x32_bf16(va0, pf, acc0[qf], 0, 0, 0);
            acc1[qf] = __builtin_amdgcn_mfma_f32_16x16x32_bf16(va1, pf, acc1[qf], 0, 0, 0);
        }
    }

    const int b = bh >> 2, h = bh & 3;
    #pragma unroll
    for (int qf = 0; qf < 4; ++qf) {
        float ls = lsum[qf];
        ls += __shfl_xor(ls, 16);
        ls += __shfl_xor(ls, 32);
        const float inv = 1.0f / ls;
        const int qrow = w * 64 + qf * 16 + l15;
        short* cg = ctxbf + (((size_t)(e * B_ + b) * S_ + qrow) * D_ + h * DH_);
        bf16x4 o0, o1;
        #pragma unroll
        for (int r = 0; r < 4; ++r) {
            o0[r] = f2bf(acc0[qf][r] * inv);
            o1[r] = f2bf(acc1[qf][r] * inv);
        }
        *(bf16x4*)&cg[4 * g]      = o0;
        *(bf16x4*)&cg[16 + 4 * g] = o1;
    }
}

// ---------------------------------------------------------------------------
// Kernel 3: head, 512-thr blocks, 128 rows. Dynamic LDS 69.6 KB.
// ---------------------------------------------------------------------------
__global__ __launch_bounds__(512) void head_mfma_kernel(
    const short* __restrict__ ctxbf,  // [E][4096][128] bf16
    const short* __restrict__ wobf,   // [E][128][128] bf16
    const float* __restrict__ bo,     // [E][128]
    const short* __restrict__ w1bf,   // [E][64][128] bf16
    const float* __restrict__ b1,     // [E][64]
    const float* __restrict__ W2,     // [E][64]
    const float* __restrict__ b2,     // [E]
    float* __restrict__ out)          // [B][S][E]
{
    extern __shared__ __align__(16) char smem[];
    short (*Wos)[136] = (short(*)[136])smem;                  // [128][136]
    short (*cts)[136] = (short(*)[136])(smem + 128 * 136 * 2);

    const int mt  = blockIdx.x;   // 0..31 (128-row tiles)
    const int e   = blockIdx.y;
    const int tid = threadIdx.x;
    const int w    = tid >> 6;
    const int lane = tid & 63;
    const int l15  = lane & 15;
    const int g    = lane >> 4;

    #pragma unroll
    for (int p = 0; p < 4; ++p) {
        int idx = tid + p * 512;           // 2048 chunks
        int row = idx >> 4, c8 = (idx & 15) * 8;
        *(bf16x8*)&Wos[row][c8] =
            *(const bf16x8*)&wobf[((size_t)e * 128 + row) * 128 + c8];
        *(bf16x8*)&cts[row][c8] =
            *(const bf16x8*)&ctxbf[((size_t)e * M_ + mt * 128 + row) * 128 + c8];
    }
    __syncthreads();

    // ---- Phase A: attended = ctx @ Wo^T, rows w*16+l15 ----
    f32x4 accA[8] = {};
    #pragma unroll
    for (int kk = 0; kk < 128; kk += 32) {
        bf16x8 a = cat8(*(const bf16x4*)&cts[w * 16 + l15][kk + 4 * g],
                        *(const bf16x4*)&cts[w * 16 + l15][kk + 16 + 4 * g]);
        #pragma unroll
        for (int t = 0; t < 8; ++t) {
            bf16x8 bfr = cat8(*(const bf16x4*)&Wos[t * 16 + l15][kk + 4 * g],
                              *(const bf16x4*)&Wos[t * 16 + l15][kk + 16 + 4 * g]);
            accA[t] = __builtin_amdgcn_mfma_f32_16x16x32_bf16(a, bfr, accA[t], 0, 0, 0);
        }
    }
    __syncthreads();

    // ---- restage W1 into Wos rows 0..63; write attended into cts ----
    #pragma unroll
    for (int p = 0; p < 2; ++p) {
        int idx = tid + p * 512;           // 1024 chunks
        int row = idx >> 4, c8 = (idx & 15) * 8;
        *(bf16x8*)&Wos[row][c8] =
            *(const bf16x8*)&w1bf[((size_t)e * 64 + row) * 128 + c8];
    }
    #pragma unroll
    for (int t = 0; t < 8; ++t) {
        const float bov = bo[e * 128 + t * 16 + l15];
        #pragma unroll
        for (int r = 0; r < 4; ++r)
            cts[w * 16 + 4 * g + r][t * 16 + l15] = f2bf(accA[t][r] + bov);
    }
    __syncthreads();

    // ---- Phase B: h = relu(att @ W1^T + b1) ----
    f32x4 accB[4] = {};
    #pragma unroll
    for (int kk = 0; kk < 128; kk += 32) {
        bf16x8 a = cat8(*(const bf16x4*)&cts[w * 16 + l15][kk + 4 * g],
                        *(const bf16x4*)&cts[w * 16 + l15][kk + 16 + 4 * g]);
        #pragma unroll
        for (int t = 0; t < 4; ++t) {
            bf16x8 bfr = cat8(*(const bf16x4*)&Wos[t * 16 + l15][kk + 4 * g],
                              *(const bf16x4*)&Wos[t * 16 + l15][kk + 16 + 4 * g]);
            accB[t] = __builtin_amdgcn_mfma_f32_16x16x32_bf16(a, bfr, accB[t], 0, 0, 0);
        }
    }

    // ---- Phase C: logits ----
    float b1v[4], w2v[4];
    #pragma unroll
    for (int t = 0; t < 4; ++t) {
        b1v[t] = b1[e * 64 + t * 16 + l15];
        w2v[t] = W2[e * 64 + t * 16 + l15];
    }
    const float b2v = b2[e];
    #pragma unroll
    for (int r = 0; r < 4; ++r) {
        float s = 0.f;
        #pragma unroll
        for (int t = 0; t < 4; ++t)
            s += fmaxf(accB[t][r] + b1v[t], 0.f) * w2v[t];
        s += __shfl_xor(s, 1);
        s += __shfl_xor(s, 2);
        s += __shfl_xor(s, 4);
        s += __shfl_xor(s, 8);
        if (l15 == 0) {
            const int m = mt * 128 + w * 16 + 4 * g + r;
            const int bb = m >> 9, ss = m & 511;
            out[((size_t)(bb * S_ + ss)) * E_ + e] = s + b2v;
        }
    }
}

// ---------------------------------------------------------------------------
extern "C" void kernel_launch(void* const* d_in, const int* in_sizes, int n_in,
                              void* d_out, int out_size, void* d_ws, size_t ws_size,
                              hipStream_t stream) {
    const float* x    = (const float*)d_in[0];
    const float* Wqkv = (const float*)d_in[1];
    const float* bqkv = (const float*)d_in[2];
    const float* Wo   = (const float*)d_in[3];
    const float* bo   = (const float*)d_in[4];
    const float* W1   = (const float*)d_in[5];
    const float* b1   = (const float*)d_in[6];
    const float* W2   = (const float*)d_in[7];
    const float* b2   = (const float*)d_in[8];
    float* out = (float*)d_out;

    const size_t SZ = (size_t)E_ * B_ * H_ * S_ * DH_;  // 8,388,608 elements
    short* qb    = (short*)d_ws;
    short* kb    = qb + SZ;
    short* vtb   = kb + SZ;
    short* ctxbf = vtb + SZ;                 // [E][4096][128] bf16
    short* xbf   = ctxbf + SZ;               // 524288
    short* wbf   = xbf + (size_t)M_ * D_;    // 786432
    short* wobf  = wbf + (size_t)E_ * 3 * D_ * D_;   // 262144
    short* w1bf  = wobf + (size_t)E_ * D_ * D_;      // 131072

    hipFuncSetAttribute((const void*)attn_kernel,
                        hipFuncAttributeMaxDynamicSharedMemorySize,
                        ATTN_LDS_BYTES);
    hipFuncSetAttribute((const void*)head_mfma_kernel,
                        hipFuncAttributeMaxDynamicSharedMemorySize,
                        HEAD_LDS_BYTES);

    convert_kernel<<<dim3(832), 256, 0, stream>>>(x, Wqkv, Wo, W1, xbf, wbf, wobf, w1bf);
    qkv_mfma_kernel<<<dim3(6, 32, 16), 512, 0, stream>>>(xbf, wbf, bqkv, qb, kb, vtb);
    attn_kernel<<<dim3(32, 16), 512, ATTN_LDS_BYTES, stream>>>(qb, kb, vtb, ctxbf);
    head_mfma_kernel<<<dim3(32, 16), 512, HEAD_LDS_BYTES, stream>>>(ctxbf, wobf, bo, w1bf, b1, W2, b2, out);
}